// Round 8
// baseline (73.135 us; speedup 1.0000x reference)
//
#include <hip/hip_runtime.h>

#define D 128
#define NS 16
#define BATCH 16384
#define TILE 64
#define CHUNK 1024

typedef __attribute__((ext_vector_type(8))) short short8;
typedef __attribute__((ext_vector_type(4))) float f32x4;

__device__ __forceinline__ unsigned short f2bf(float f) {
  unsigned u = __builtin_bit_cast(unsigned, f);
  u += 0x7FFFu + ((u >> 16) & 1u);   // round-to-nearest-even
  return (unsigned short)(u >> 16);
}

__device__ __forceinline__ uint4 pack8(float4 a, float4 b) {
  unsigned short p[8];
  p[0] = f2bf(a.x); p[1] = f2bf(a.y); p[2] = f2bf(a.z); p[3] = f2bf(a.w);
  p[4] = f2bf(b.x); p[5] = f2bf(b.y); p[6] = f2bf(b.z); p[7] = f2bf(b.w);
  return *(const uint4*)p;
}

// ---------------------------------------------------------------------------
// R8: final cell of the (traffic x occupancy) grid.
//  - 256 blocks x 512 threads, CHUNK=1024: 1 block/CU, 8 waves = 2 waves/SIMD
//    (R5/R7's established-sufficient occupancy) with HALF the aggregate
//    weight-gather traffic (32 MB vs R5/R7's 64 MB) and half the per-block
//    launches. R6 tested this traffic economy at 1 wave/SIMD and regressed;
//    this restores the occupancy via block width instead of block count.
//  - wave w (0..7) owns cols w*16..+15; 64 weight loads/thread (as R7).
//  - cnt ~ Bin(1024,1/16) = 64 +- 7.7; TILE=64 with block-uniform stripe-skip
//    guards for the ~50%-probable small second pass (R6-validated).
//  - XOR-swizzled XH (R3-validated), reg-resident bf16 B-frags (R5-validated).
//  MFMA 16x16x32 bf16 layouts (HW-verified):
//    A: A[m=lane&15][k=(lane>>4)*8+j]   B: B[k=(lane>>4)*8+j][n=lane&15]
//    C/D: col=lane&15, row=(lane>>4)*4+reg
//  LDS: XH 16K + rowlist 4K + wcnt = 20.3K (1 block/CU).
// ---------------------------------------------------------------------------
__global__ __launch_bounds__(512, 2) void ssm_fused(
    const float* __restrict__ x,
    const int* __restrict__ sidx,
    const float* __restrict__ A_all,
    const float* __restrict__ C_all,
    float* __restrict__ out) {
  __shared__ unsigned short XH[TILE * D];   // [row][chunk ^ (row&15)][8]
  __shared__ int rowlist[CHUNK];
  __shared__ int wcnt[16];

  const int b = blockIdx.x;
  const int s = (b & 7) | (((b >> 3) & 1) << 3);  // same-state blocks same XCD
  const int c0 = (b >> 4) * CHUNK;
  const int tid = threadIdx.x;
  const int lane = tid & 63, w = tid >> 6;        // w in [0,8)
  const int l15 = lane & 15, quad = lane >> 4;

  // ---- 1. scan chunk: 512 threads x 2 loads cover CHUNK=1024 ----
  const int v0 = sidx[c0 + tid];
  const int v1 = sidx[c0 + 512 + tid];

  // ---- 2. B-fragments for BOTH phases, direct fp32 -> bf16 regs ----
  // frag kb: elems A[k = kb*32 + quad*8 + j][col = w*16 + l15]
  short8 aW[4], cW[4];
  {
    const size_t wb = (size_t)s * D * D;
    const int col = w * 16 + l15;
#pragma unroll
    for (int kb = 0; kb < 4; kb++) {
      const float* pA = A_all + wb + (size_t)(kb * 32 + quad * 8) * D + col;
      const float* pC = C_all + wb + (size_t)(kb * 32 + quad * 8) * D + col;
      unsigned short ta[8], tc[8];
#pragma unroll
      for (int j = 0; j < 8; j++) {
        ta[j] = f2bf(pA[j * D]);
        tc[j] = f2bf(pC[j * D]);
      }
      aW[kb] = *(const short8*)ta;
      cW[kb] = *(const short8*)tc;
    }
  }

  // ---- ballot compaction (2 groups x 8 waves; order j = g*8 + w) ----
  const unsigned long long lanelt = (1ull << lane) - 1ull;
  const unsigned long long m0 = __ballot(v0 == s);
  const unsigned long long m1 = __ballot(v1 == s);
  if (lane == 0) { wcnt[w] = (int)__popcll(m0); wcnt[8 + w] = (int)__popcll(m1); }
  __syncthreads();  // wcnt ready
  int pre0 = 0, pre1 = 0, tot0 = 0, cnt = 0;
#pragma unroll
  for (int ww = 0; ww < 8; ww++) {
    if (ww < w) { pre0 += wcnt[ww]; pre1 += wcnt[8 + ww]; }
    tot0 += wcnt[ww];
    cnt += wcnt[ww] + wcnt[8 + ww];
  }
  if (v0 == s) rowlist[pre0 + (int)__popcll(m0 & lanelt)] = c0 + tid;
  if (v1 == s) rowlist[tot0 + pre1 + (int)__popcll(m1 & lanelt)] = c0 + 512 + tid;
  if (cnt == 0) return;  // block-uniform

  // ---- 3. MFMA tiles (E[passes] ~ 1.5; spill pass stripe-skipped) ----
#pragma unroll 1
  for (int i0 = 0; i0 < cnt; i0 += TILE) {
    __syncthreads();  // rowlist ready (pass 0) / prior pass XH reads done

    // stripe-valid flags (block-uniform)
    const bool tv1 = (i0 + 16 < cnt), tv2 = (i0 + 32 < cnt), tv3 = (i0 + 48 < cnt);

    // gather 64 X rows (8 threads/row, 16 elems each), XOR-swizzled chunks
    {
      const int r = tid >> 3, q8 = tid & 7;
      const int rid = (i0 + r < cnt) ? rowlist[i0 + r] : -1;
      const int cA = q8 * 2, cB = q8 * 2 + 1;
      uint4* dA = (uint4*)&XH[r * D + ((cA ^ (r & 15)) << 3)];
      uint4* dB = (uint4*)&XH[r * D + ((cB ^ (r & 15)) << 3)];
      if (rid >= 0) {
        const float4* src = (const float4*)(x + (size_t)rid * D + q8 * 16);
        *dA = pack8(src[0], src[1]);
        *dB = pack8(src[2], src[3]);
      } else {
        uint4 z = {0, 0, 0, 0};
        *dA = z;
        *dB = z;
      }
    }
    __syncthreads();  // X ready

    // phase 1: acc = X @ A ; wave w: all 64 rows, cols w*16..+15
    f32x4 acc[4];
#pragma unroll
    for (int ti = 0; ti < 4; ti++) acc[ti] = (f32x4){0.f, 0.f, 0.f, 0.f};
#pragma unroll
    for (int kb = 0; kb < 4; kb++) {
      short8 aF[4];
#pragma unroll
      for (int ti = 0; ti < 4; ti++) {
        if (ti == 1 && !tv1) continue;
        if (ti == 2 && !tv2) continue;
        if (ti == 3 && !tv3) continue;
        aF[ti] = *(const short8*)&XH[(ti * 16 + l15) * D +
                                     (((kb * 4 + quad) ^ l15) << 3)];
      }
#pragma unroll
      for (int ti = 0; ti < 4; ti++) {
        if (ti == 1 && !tv1) continue;
        if (ti == 2 && !tv2) continue;
        if (ti == 3 && !tv3) continue;
        acc[ti] = __builtin_amdgcn_mfma_f32_16x16x32_bf16(aF[ti], aW[kb],
                                                          acc[ti], 0, 0, 0);
      }
    }
    __syncthreads();  // all phase-1 XH(X) reads done (XH reused for H)

    // H = relu(acc) -> XH, swizzle-consistent scalar writes
#pragma unroll
    for (int ti = 0; ti < 4; ti++) {
      if (ti == 1 && !tv1) continue;
      if (ti == 2 && !tv2) continue;
      if (ti == 3 && !tv3) continue;
#pragma unroll
      for (int rr = 0; rr < 4; rr++) {
        float v = acc[ti][rr];
        const int row = ti * 16 + quad * 4 + rr;
        const int ch = (w * 2 + (l15 >> 3)) ^ (quad * 4 + rr);
        XH[row * D + (ch << 3) + (l15 & 7)] = f2bf(v > 0.f ? v : 0.f);
      }
    }
    __syncthreads();  // H ready

    // phase 2: out = H @ C
#pragma unroll
    for (int ti = 0; ti < 4; ti++) acc[ti] = (f32x4){0.f, 0.f, 0.f, 0.f};
#pragma unroll
    for (int kb = 0; kb < 4; kb++) {
      short8 aF[4];
#pragma unroll
      for (int ti = 0; ti < 4; ti++) {
        if (ti == 1 && !tv1) continue;
        if (ti == 2 && !tv2) continue;
        if (ti == 3 && !tv3) continue;
        aF[ti] = *(const short8*)&XH[(ti * 16 + l15) * D +
                                     (((kb * 4 + quad) ^ l15) << 3)];
      }
#pragma unroll
      for (int ti = 0; ti < 4; ti++) {
        if (ti == 1 && !tv1) continue;
        if (ti == 2 && !tv2) continue;
        if (ti == 3 && !tv3) continue;
        acc[ti] = __builtin_amdgcn_mfma_f32_16x16x32_bf16(aF[ti], cW[kb],
                                                          acc[ti], 0, 0, 0);
      }
    }

    // scatter stores (fp32; 16 consecutive lanes -> 64B segments)
#pragma unroll
    for (int ti = 0; ti < 4; ti++) {
      if (ti == 1 && !tv1) continue;
      if (ti == 2 && !tv2) continue;
      if (ti == 3 && !tv3) continue;
#pragma unroll
      for (int rr = 0; rr < 4; rr++) {
        const int rl = i0 + ti * 16 + quad * 4 + rr;
        if (rl < cnt) {
          out[(size_t)rowlist[rl] * D + w * 16 + l15] = acc[ti][rr];
        }
      }
    }
  }
}

extern "C" void kernel_launch(void* const* d_in, const int* in_sizes, int n_in,
                              void* d_out, int out_size, void* d_ws, size_t ws_size,
                              hipStream_t stream) {
  const float* x = (const float*)d_in[0];
  const int* sidx = (const int*)d_in[1];
  const float* A_all = (const float*)d_in[2];
  const float* C_all = (const float*)d_in[3];
  float* out = (float*)d_out;

  ssm_fused<<<BATCH / CHUNK * NS, 512, 0, stream>>>(x, sidx, A_all, C_all, out);
}

// Round 9
// 71.838 us; speedup vs baseline: 1.0181x; 1.0181x over previous
//
#include <hip/hip_runtime.h>

#define D 128
#define NS 16
#define BATCH 16384
#define TILE 64
#define CHUNK 512

typedef __attribute__((ext_vector_type(8))) short short8;
typedef __attribute__((ext_vector_type(4))) float f32x4;

__device__ __forceinline__ unsigned short f2bf(float f) {
  unsigned u = __builtin_bit_cast(unsigned, f);
  u += 0x7FFFu + ((u >> 16) & 1u);   // round-to-nearest-even
  return (unsigned short)(u >> 16);
}

__device__ __forceinline__ uint4 pack8(float4 a, float4 b) {
  unsigned short p[8];
  p[0] = f2bf(a.x); p[1] = f2bf(a.y); p[2] = f2bf(a.z); p[3] = f2bf(a.w);
  p[4] = f2bf(b.x); p[5] = f2bf(b.y); p[6] = f2bf(b.z); p[7] = f2bf(b.w);
  return *(const uint4*)p;
}

// ---------------------------------------------------------------------------
// R9 = R7 (best: 512 blocks x 512 threads, CHUNK 512, 4 waves/SIMD,
// reg-resident bf16 B-frags, XOR-swizzled XH) + ONE change:
//  - cW gather deferred into the tile loop, issued after phase-1 MFMAs and
//    before the WAR barrier -> its 32-load latency chain hides under
//    barrier + H-store + barrier instead of serializing in the prologue
//    (placement validated in R5). Prologue weight chain halves (32 loads).
//  Session model (9 configs): dur = fill(42, harness) + memset(1.3) +
//  graph/dispatch overhead(~15-20) + kernel(~6-8). All pipe counters <10%;
//  kernel is cold-L3 latency-bound (268MB poison fill evicts L3 each replay).
//  MFMA 16x16x32 bf16 layouts (HW-verified):
//    A: A[m=lane&15][k=(lane>>4)*8+j]   B: B[k=(lane>>4)*8+j][n=lane&15]
//    C/D: col=lane&15, row=(lane>>4)*4+reg
//  LDS: XH 16K + rowlist 2K + wcnt = 18.1K (2 blocks/CU).
// ---------------------------------------------------------------------------
__global__ __launch_bounds__(512, 4) void ssm_fused(
    const float* __restrict__ x,
    const int* __restrict__ sidx,
    const float* __restrict__ A_all,
    const float* __restrict__ C_all,
    float* __restrict__ out) {
  __shared__ unsigned short XH[TILE * D];   // [row][chunk ^ (row&15)][8]
  __shared__ int rowlist[CHUNK];
  __shared__ int wcnt[8];

  const int b = blockIdx.x;
  const int s = (b & 7) | (((b >> 3) & 1) << 3);  // same-state blocks same XCD
  const int c0 = (b >> 4) * CHUNK;
  const int tid = threadIdx.x;
  const int lane = tid & 63, w = tid >> 6;        // w in [0,8)
  const int l15 = lane & 15, quad = lane >> 4;

  // ---- 1. scan chunk: 512 threads cover CHUNK with one load each ----
  const int v0 = sidx[c0 + tid];

  // ---- 2. phase-1 B-fragments only (cW deferred into the tile loop) ----
  // frag kb: elems A[k = kb*32 + quad*8 + j][col = w*16 + l15]
  const size_t wb = (size_t)s * D * D;
  const int col = w * 16 + l15;
  const float* __restrict__ pAb = A_all + wb + col + (size_t)(quad * 8) * D;
  const float* __restrict__ pCb = C_all + wb + col + (size_t)(quad * 8) * D;
  short8 aW[4];
#pragma unroll
  for (int kb = 0; kb < 4; kb++) {
    const float* pA = pAb + (size_t)(kb * 32) * D;
    unsigned short ta[8];
#pragma unroll
    for (int j = 0; j < 8; j++) ta[j] = f2bf(pA[j * D]);
    aW[kb] = *(const short8*)ta;
  }

  // ---- ballot compaction (8 waves) ----
  const unsigned long long lanelt = (1ull << lane) - 1ull;
  const unsigned long long m0 = __ballot(v0 == s);
  if (lane == 0) wcnt[w] = (int)__popcll(m0);
  __syncthreads();  // wcnt ready
  int pre = 0, cnt = 0;
#pragma unroll
  for (int ww = 0; ww < 8; ww++) {
    const int c = wcnt[ww];
    if (ww < w) pre += c;
    cnt += c;
  }
  if (v0 == s) rowlist[pre + (int)__popcll(m0 & lanelt)] = c0 + tid;
  if (cnt == 0) return;  // block-uniform

  // ---- 3. MFMA tiles (E[cnt]=32: one 64-row pass ~always) ----
#pragma unroll 1
  for (int i0 = 0; i0 < cnt; i0 += TILE) {
    __syncthreads();  // rowlist ready (pass 0) / prior pass XH reads done

    // gather 64 X rows (8 threads/row, 16 elems each), XOR-swizzled chunks
    {
      const int r = tid >> 3, q8 = tid & 7;
      const int rid = (i0 + r < cnt) ? rowlist[i0 + r] : -1;
      const int cA = q8 * 2, cB = q8 * 2 + 1;
      uint4* dA = (uint4*)&XH[r * D + ((cA ^ (r & 15)) << 3)];
      uint4* dB = (uint4*)&XH[r * D + ((cB ^ (r & 15)) << 3)];
      if (rid >= 0) {
        const float4* src = (const float4*)(x + (size_t)rid * D + q8 * 16);
        *dA = pack8(src[0], src[1]);
        *dB = pack8(src[2], src[3]);
      } else {
        uint4 z = {0, 0, 0, 0};
        *dA = z;
        *dB = z;
      }
    }
    __syncthreads();  // X ready

    // phase 1: acc = X @ A ; wave w: all 64 rows, cols w*16..+15
    f32x4 acc[4];
#pragma unroll
    for (int ti = 0; ti < 4; ti++) acc[ti] = (f32x4){0.f, 0.f, 0.f, 0.f};
#pragma unroll
    for (int kb = 0; kb < 4; kb++) {
      short8 aF[4];
#pragma unroll
      for (int ti = 0; ti < 4; ti++)
        aF[ti] = *(const short8*)&XH[(ti * 16 + l15) * D +
                                     (((kb * 4 + quad) ^ l15) << 3)];
#pragma unroll
      for (int ti = 0; ti < 4; ti++)
        acc[ti] = __builtin_amdgcn_mfma_f32_16x16x32_bf16(aF[ti], aW[kb],
                                                          acc[ti], 0, 0, 0);
    }

    // phase-2 B-frags now: latency hides under barrier + H-store + barrier
    short8 cW[4];
#pragma unroll
    for (int kb = 0; kb < 4; kb++) {
      const float* pC = pCb + (size_t)(kb * 32) * D;
      unsigned short tc[8];
#pragma unroll
      for (int j = 0; j < 8; j++) tc[j] = f2bf(pC[j * D]);
      cW[kb] = *(const short8*)tc;
    }

    __syncthreads();  // all phase-1 XH(X) reads done (XH reused for H)

    // H = relu(acc) -> XH, swizzle-consistent scalar writes
#pragma unroll
    for (int ti = 0; ti < 4; ti++)
#pragma unroll
      for (int rr = 0; rr < 4; rr++) {
        float v = acc[ti][rr];
        const int row = ti * 16 + quad * 4 + rr;
        const int ch = (w * 2 + (l15 >> 3)) ^ (quad * 4 + rr);
        XH[row * D + (ch << 3) + (l15 & 7)] = f2bf(v > 0.f ? v : 0.f);
      }
    __syncthreads();  // H ready

    // phase 2: out = H @ C
#pragma unroll
    for (int ti = 0; ti < 4; ti++) acc[ti] = (f32x4){0.f, 0.f, 0.f, 0.f};
#pragma unroll
    for (int kb = 0; kb < 4; kb++) {
      short8 aF[4];
#pragma unroll
      for (int ti = 0; ti < 4; ti++)
        aF[ti] = *(const short8*)&XH[(ti * 16 + l15) * D +
                                     (((kb * 4 + quad) ^ l15) << 3)];
#pragma unroll
      for (int ti = 0; ti < 4; ti++)
        acc[ti] = __builtin_amdgcn_mfma_f32_16x16x32_bf16(aF[ti], cW[kb],
                                                          acc[ti], 0, 0, 0);
    }

    // scatter stores (fp32; 16 consecutive lanes -> 64B segments)
#pragma unroll
    for (int ti = 0; ti < 4; ti++)
#pragma unroll
      for (int rr = 0; rr < 4; rr++) {
        const int rl = i0 + ti * 16 + quad * 4 + rr;
        if (rl < cnt) {
          out[(size_t)rowlist[rl] * D + w * 16 + l15] = acc[ti][rr];
        }
      }
  }
}

extern "C" void kernel_launch(void* const* d_in, const int* in_sizes, int n_in,
                              void* d_out, int out_size, void* d_ws, size_t ws_size,
                              hipStream_t stream) {
  const float* x = (const float*)d_in[0];
  const int* sidx = (const int*)d_in[1];
  const float* A_all = (const float*)d_in[2];
  const float* C_all = (const float*)d_in[3];
  float* out = (float*)d_out;

  ssm_fused<<<BATCH / CHUNK * NS, 512, 0, stream>>>(x, sidx, A_all, C_all, out);
}